// Round 5
// baseline (455.473 us; speedup 1.0000x reference)
//
#include <hip/hip_runtime.h>

#define D      128
#define NINIT  100000
#define LVLS   64
#define M      4096
#define NRULES 256
#define NTOT   (NINIT + LVLS * M)
#define NTHR   512

typedef __attribute__((ext_vector_type(8))) short short8;   // 8 bf16 = 4 VGPRs
typedef __attribute__((ext_vector_type(4))) float floatx4;  // MFMA accumulator

// ---------------------------------------------------------------------------
// ws layout (bytes):
//   0      : sums[2] fp32
//   128    : barrier cnt (u32), barrier gen (u32)       (own cacheline)
//   256    : store  bf16 [NTOT][128]          (92,708,864 B)
//   SI_OFF : sorted_idx int [LVLS][M]          (1,048,576 B)
//   RO_OFF : rule_off  int [LVLS][NRULES+1]       (65,792 B)
//   FL_OFF : ready-flags u32 [LVLS*M]          (1,048,576 B)  (memset 0)
// ---------------------------------------------------------------------------
#define ST_OFF 256
#define SI_OFF (ST_OFF + (size_t)NTOT * D * 2)
#define RO_OFF (SI_OFF + (size_t)LVLS * M * 4)
#define FL_OFF (RO_OFF + (size_t)LVLS * (NRULES + 1) * 4)

__device__ __forceinline__ unsigned short f2bf(float x) {  // RNE fp32->bf16
  unsigned u = __float_as_uint(x);
  u += 0x7fffu + ((u >> 16) & 1u);
  return (unsigned short)(u >> 16);
}

__device__ __forceinline__ float softplusf(float x) {
  return fmaxf(x, 0.f) + log1pf(expf(-fabsf(x)));
}

// --- LLC-coherent (cross-XCD) primitives. SYSTEM-scope relaxed atomics emit
// sc0 sc1 accesses: stores write through to the Infinity Cache (coherence
// point for all 8 XCDs), loads bypass L1/L2 and read it directly.
__device__ __forceinline__ void st_sys(unsigned* p, unsigned v) {
  __hip_atomic_store(p, v, __ATOMIC_RELAXED, __HIP_MEMORY_SCOPE_SYSTEM);
}
__device__ __forceinline__ unsigned ld_sys(const unsigned* p) {
  return __hip_atomic_load(p, __ATOMIC_RELAXED, __HIP_MEMORY_SCOPE_SYSTEM);
}
// Spin with a cap: a protocol bug becomes a wrong answer, not a harness hang.
__device__ __forceinline__ void wait_flag(const unsigned* f) {
  int guard = 1 << 17;
  while (__builtin_expect(ld_sys(f) == 0u, 0) && --guard)
    __builtin_amdgcn_s_sleep(2);
  asm volatile("" ::: "memory");
}

// Heavy grid barrier (release/acquire, flushes+invalidates each XCD's L2).
// Used ONCE, after the init phases: publishes normal-store init data AND
// flushes harness-poison / memset lines, which the flag protocol relies on.
__device__ __forceinline__ void gbar_heavy(unsigned* bcnt, unsigned* bgen) {
  __syncthreads();
  if (threadIdx.x == 0) {
    unsigned g = __hip_atomic_load(bgen, __ATOMIC_RELAXED, __HIP_MEMORY_SCOPE_AGENT);
    unsigned v = __hip_atomic_fetch_add(bcnt, 1u, __ATOMIC_ACQ_REL, __HIP_MEMORY_SCOPE_AGENT);
    if (v == gridDim.x - 1) {
      __hip_atomic_store(bcnt, 0u, __ATOMIC_RELAXED, __HIP_MEMORY_SCOPE_AGENT);
      __hip_atomic_fetch_add(bgen, 1u, __ATOMIC_ACQ_REL, __HIP_MEMORY_SCOPE_AGENT);
    } else {
      while (__hip_atomic_load(bgen, __ATOMIC_RELAXED, __HIP_MEMORY_SCOPE_AGENT) == g)
        __builtin_amdgcn_s_sleep(1);
      __builtin_amdgcn_fence(__ATOMIC_ACQUIRE, "agent");
    }
  }
  __syncthreads();
}

// Light barrier before loss: fence-free (derived rows already at the LLC via
// sc0 stores; consumer caches hold only legally-read clean lines).
__device__ __forceinline__ void gbar_light(unsigned* bcnt, unsigned* bgen) {
  __syncthreads();  // drains vmcnt: this block's stores are out
  if (threadIdx.x == 0) {
    unsigned g = ld_sys(bgen);
    unsigned v = __hip_atomic_fetch_add(bcnt, 1u, __ATOMIC_RELAXED,
                                        __HIP_MEMORY_SCOPE_SYSTEM);
    if (v == gridDim.x - 1) {
      st_sys(bcnt, 0u);
      st_sys(bgen, g + 1u);
    } else {
      int guard = 1 << 22;
      while (ld_sys(bgen) == g && --guard) __builtin_amdgcn_s_sleep(2);
    }
  }
  __syncthreads();
}

// Cursor over this block's tiles: rule r, tile-parity par, stride PAIR tiles.
template <int PAIR>
__device__ __forceinline__ bool adv_cursor(int par, int r,
                                           const int* __restrict__ ro, int& l,
                                           int& t0, int& off, int& cnt) {
  t0 += 16 * PAIR;
  while (t0 >= cnt) {
    if (++l >= LVLS) return false;
    off = ro[l * (NRULES + 1) + r];
    cnt = ro[l * (NRULES + 1) + r + 1] - off;
    t0 = 16 * par;
  }
  return true;
}

// One cooperative kernel. Rule rr is owned by PAIR blocks (B-fragments
// persistent in 32 VGPRs each); tiles stream through a depth-3 software
// pipeline with next-tile loads issued BEFORE the MFMA so their latency
// hides under compute + the writeback drain. PAIR=2 gives 2 blocks/CU.
template <int PAIR>
__global__ __launch_bounds__(NTHR, 4) void fused_kernel(
    const float* __restrict__ thax_table, const float* __restrict__ sine_table,
    const float* __restrict__ rule_W, const float* __restrict__ rule_b,
    const float* __restrict__ eval_w, const float* __restrict__ eval_b,
    const float* __restrict__ pos, const float* __restrict__ neg,
    const int* __restrict__ init_thax, const int* __restrict__ init_sine,
    const int* __restrict__ parents,  // [LVLS][M][2]
    const int* __restrict__ rules,    // [LVLS][M]
    unsigned short* __restrict__ store, int* __restrict__ sorted_idx,
    int* __restrict__ rule_off, unsigned* __restrict__ flags,
    float* __restrict__ sums, unsigned* __restrict__ bvars,
    float* __restrict__ out) {
  __shared__ unsigned short pe[2 * 16 * 264];  // double-buffered gather tile
  __shared__ unsigned short ot[16 * 136];      // output tile (transpose)
  __shared__ int s_sid[2][16];
  __shared__ int s_cnt[NRULES];
  __shared__ int s_base[NRULES + 1];
  __shared__ float racc[3];

  unsigned* bcnt = bvars;
  unsigned* bgen = bvars + 1;

  const int r = blockIdx.x >> (PAIR - 1);   // owning rule
  const int par = blockIdx.x & (PAIR - 1);  // tile parity within the rule
  const int tid = threadIdx.x;
  const int wave = tid >> 6, lane = tid & 63;
  const int col = (wave << 4) + (lane & 15);
  const int snode = tid >> 5, seg = tid & 31;  // staging role: 1 uint4/thread
  const int half = seg >> 4;                   // which of the 2 parents
  const int gid = blockIdx.x * NTHR + tid;
  const int gthreads = gridDim.x * NTHR;

  // ---- Phase A1: rule-r weight fragments, fp32 global -> bf16 VGPRs (once).
  short8 bf[8];
  {
    const float* Wr = rule_W + (size_t)r * (2 * D * D);
    const int krow_base = (lane >> 4) * 8;
#pragma unroll
    for (int ks = 0; ks < 8; ++ks) {
      union { short8 s; unsigned short us[8]; } c;
#pragma unroll
      for (int j = 0; j < 8; ++j)
        c.us[j] = f2bf(Wr[(size_t)(ks * 32 + krow_base + j) * D + col]);
      bf[ks] = c.s;
    }
  }
  const float bias = rule_b[r * D + col];

  // ---- Phase A2: counting-sort nodes by rule (blocks 0..63, one level each).
  if (blockIdx.x < LVLS) {
    const int l = blockIdx.x;
    const int* rl = rules + (size_t)l * M;
    if (tid < NRULES) s_cnt[tid] = 0;
    __syncthreads();
    for (int m = tid; m < M; m += NTHR) atomicAdd(&s_cnt[rl[m]], 1);
    __syncthreads();
    if (tid == 0) {
      int run = 0;
      for (int q = 0; q < NRULES; ++q) { s_base[q] = run; run += s_cnt[q]; }
      s_base[NRULES] = run;
    }
    __syncthreads();
    if (tid < NRULES) {
      rule_off[(size_t)l * (NRULES + 1) + tid] = s_base[tid];
      s_cnt[tid] = s_base[tid];
    }
    if (tid == 0) rule_off[(size_t)l * (NRULES + 1) + NRULES] = M;
    __syncthreads();
    for (int m = tid; m < M; m += NTHR) {
      int p = atomicAdd(&s_cnt[rl[m]], 1);
      sorted_idx[(size_t)l * M + p] = m;
    }
  }

  // ---- Phase A3: init-node embeddings (all blocks, grid-stride).
  for (int idx = gid; idx < NINIT * 16; idx += gthreads) {
    int node = idx >> 4, sg = idx & 15;
    const float4* t = (const float4*)(thax_table + (size_t)init_thax[node] * D) + sg * 2;
    const float4* s = (const float4*)(sine_table + (size_t)init_sine[node] * D) + sg * 2;
    float4 a0 = t[0], a1 = t[1], b0 = s[0], b1 = s[1];
    float v[8] = {a0.x + b0.x, a0.y + b0.y, a0.z + b0.z, a0.w + b0.w,
                  a1.x + b1.x, a1.y + b1.y, a1.z + b1.z, a1.w + b1.w};
    uint4 pk;
    pk.x = (unsigned)f2bf(v[0]) | ((unsigned)f2bf(v[1]) << 16);
    pk.y = (unsigned)f2bf(v[2]) | ((unsigned)f2bf(v[3]) << 16);
    pk.z = (unsigned)f2bf(v[4]) | ((unsigned)f2bf(v[5]) << 16);
    pk.w = (unsigned)f2bf(v[6]) | ((unsigned)f2bf(v[7]) << 16);
    *(uint4*)(store + (size_t)node * D + sg * 8) = pk;
  }

  // ---- Phase A4: pos/neg sums.
  {
    float sp = 0.f, sn = 0.f;
    for (int i = gid; i < NTOT; i += gthreads) {
      sp += pos[i];
      sn += neg[i];
    }
    for (int m = 32; m; m >>= 1) {
      sp += __shfl_xor(sp, m, 64);
      sn += __shfl_xor(sn, m, 64);
    }
    if (lane == 0) {
      atomicAdd(&sums[0], sp);
      atomicAdd(&sums[1], sn);
    }
  }

  gbar_heavy(bcnt, bgen);  // publish sort/init/sums; flush poison to LLC

  // ---- Depth-3 item pipeline over this block's tiles ---------------------
  // Slot A = item w (compute), B = w+1 (rows), C = w+2 (flags), D = w+3 (idx).
  int lL = -1, t0L = 16 * par - 16 * PAIR, offL = 0, cntL = 0;

  bool validA = adv_cursor<PAIR>(par, r, rule_off, lL, t0L, offL, cntL);
  int lA = lL, t0A = t0L, cntA = cntL;
  int parA = 0; bool lateA = false; uint4 gA = {0, 0, 0, 0};
  if (validA) {
    int gj = t0A + snode; if (gj > cntA - 1) gj = cntA - 1;
    int sid = sorted_idx[(size_t)lA * M + offL + gj];
    parA = parents[((size_t)lA * M + sid) * 2 + half];
    if (parA >= NINIT) wait_flag(flags + (parA - NINIT));
    gA = *(const uint4*)(store + (size_t)parA * D + (seg & 15) * 8);
    if (seg == 0) s_sid[0][snode] = sid;
  }

  bool validB = validA && adv_cursor<PAIR>(par, r, rule_off, lL, t0L, offL, cntL);
  int lB = lL, t0B = t0L, cntB = cntL;
  int parB = 0, sidB = 0; unsigned fB_val = 0u;  // 0 = unchecked -> late path
  if (validB) {
    int gj = t0B + snode; if (gj > cntB - 1) gj = cntB - 1;
    sidB = sorted_idx[(size_t)lB * M + offL + gj];
    parB = parents[((size_t)lB * M + sidB) * 2 + half];
  }

  bool validC = validB && adv_cursor<PAIR>(par, r, rule_off, lL, t0L, offL, cntL);
  int lC = lL, t0C = t0L, cntC = cntL;
  int parC = 0, sidC = 0;
  if (validC) {
    int gj = t0C + snode; if (gj > cntC - 1) gj = cntC - 1;
    sidC = sorted_idx[(size_t)lC * M + offL + gj];
    parC = parents[((size_t)lC * M + sidC) * 2 + half];
  }

  bool validD = validC && adv_cursor<PAIR>(par, r, rule_off, lL, t0L, offL, cntL);
  int lD = lL, t0D = t0L, offD = offL, cntD = cntL;

  int p = 0;
  while (validA) {
    // (0) late-resolve rows for A (rare). Safe: all our flags for earlier
    // items are issued, and A's parents are at strictly earlier levels.
    if (lateA) {
      wait_flag(flags + (parA - NINIT));
      gA = *(const uint4*)(store + (size_t)parA * D + (seg & 15) * 8);
    }
    // (1) stage LDS tile
    *(uint4*)(pe + p * (16 * 264) + snode * 264 + seg * 8) = gA;
    __syncthreads();
    if (validB && seg == 0) s_sid[p ^ 1][snode] = sidB;

    // (2) EARLY ISSUE: C-flag poll, B-row gathers, D-index chain. Issued
    // before the MFMA so their ~900cy LLC latency hides under compute +
    // the writeback drain; waitcnts land next iteration.
    unsigned fC_val = 1u;
    if (validC && parC >= NINIT) fC_val = ld_sys(flags + (parC - NINIT));
    bool lateB = false; uint4 gB = {0, 0, 0, 0};
    if (validB) {
      if (parB >= NINIT && fB_val == 0u) lateB = true;
      else gB = *(const uint4*)(store + (size_t)parB * D + (seg & 15) * 8);
    }
    int parD = 0, sidD = 0;
    if (validD) {
      int gj = t0D + snode; if (gj > cntD - 1) gj = cntD - 1;
      sidD = sorted_idx[(size_t)lD * M + offD + gj];
      parD = parents[((size_t)lD * M + sidD) * 2 + half];
    }

    // (3) MFMA + ReLU/bias -> transpose tile
    floatx4 acc = {0.f, 0.f, 0.f, 0.f};
#pragma unroll
    for (int ks = 0; ks < 8; ++ks) {
      short8 a = *(const short8*)(pe + p * (16 * 264) + (lane & 15) * 264 +
                                  ks * 32 + (lane >> 4) * 8);
      acc = __builtin_amdgcn_mfma_f32_16x16x32_bf16(a, bf[ks], acc, 0, 0, 0);
    }
#pragma unroll
    for (int reg = 0; reg < 4; ++reg) {
      int row = (lane >> 4) * 4 + reg;
      float v = acc[reg] + bias;
      ot[row * 136 + col] = f2bf(v > 0.f ? v : 0.f);
    }
    __syncthreads();

    // (4) per-wave: wave w owns output nodes {w, w+8} -> rows, drain, flags.
    {
      const int n_baseA = NINIT + lA * M;
      int nsid0 = s_sid[p][wave], nsid1 = s_sid[p][wave + 8];
      bool in0 = (t0A + wave) < cntA, in1 = (t0A + wave + 8) < cntA;
      if (in0)
        st_sys((unsigned*)(store + (size_t)(n_baseA + nsid0) * D) + lane,
               *(const unsigned*)(ot + wave * 136 + lane * 2));
      if (in1)
        st_sys((unsigned*)(store + (size_t)(n_baseA + nsid1) * D) + lane,
               *(const unsigned*)(ot + (wave + 8) * 136 + lane * 2));
      asm volatile("s_waitcnt vmcnt(0)" ::: "memory");  // rows at LLC
      if (lane == 0) {
        if (in0) st_sys(flags + lA * M + nsid0, 1u);
        if (in1) st_sys(flags + lA * M + nsid1, 1u);
      }
      asm volatile("" ::: "memory");  // flags issued before any later spin
    }

    // (5) shift pipeline slots
    gA = gB; lateA = lateB; parA = parB;
    lA = lB; t0A = t0B; cntA = cntB; validA = validB;
    parB = parC; sidB = sidC; fB_val = fC_val;
    lB = lC; t0B = t0C; cntB = cntC; validB = validC;
    parC = parD; sidC = sidD;
    lC = lD; t0C = t0D; cntC = cntD; validC = validD;
    validD = validC && adv_cursor<PAIR>(par, r, rule_off, lL, t0L, offL, cntL);
    lD = lL; t0D = t0L; offD = offL; cntD = cntL;
    p ^= 1;
  }

  gbar_light(bcnt, bgen);  // all rows at LLC; no fences needed

  // ---- Loss phase.
  {
    float a_loss = 0.f, a_pos = 0.f, a_neg = 0.f;
    const float pw = sums[1] / sums[0];
    const float eb = eval_b[0];
    const float4* wv = (const float4*)eval_w;

    for (int node = gid; node < NTOT; node += gthreads) {
      const uint4* v = (const uint4*)(store + (size_t)node * D);
      float dot = 0.f;
#pragma unroll
      for (int k = 0; k < 16; ++k) {
        uint4 u = v[k];
        float4 w0 = wv[k * 2], w1 = wv[k * 2 + 1];
        dot += __uint_as_float(u.x << 16) * w0.x +
               __uint_as_float(u.x & 0xffff0000u) * w0.y +
               __uint_as_float(u.y << 16) * w0.z +
               __uint_as_float(u.y & 0xffff0000u) * w0.w +
               __uint_as_float(u.z << 16) * w1.x +
               __uint_as_float(u.z & 0xffff0000u) * w1.y +
               __uint_as_float(u.w << 16) * w1.z +
               __uint_as_float(u.w & 0xffff0000u) * w1.w;
      }
      float logit = dot + eb;
      float pp = pos[node], nn = neg[node];
      float tot = pp + nn, y = pp / tot;
      a_loss += tot * (pw * y * softplusf(-logit) + (1.f - y) * softplusf(logit));
      if (logit >= 0.f) a_pos += pp; else a_neg += nn;
    }

    for (int m = 32; m; m >>= 1) {
      a_loss += __shfl_xor(a_loss, m, 64);
      a_pos  += __shfl_xor(a_pos,  m, 64);
      a_neg  += __shfl_xor(a_neg,  m, 64);
    }
    if (tid == 0) { racc[0] = 0.f; racc[1] = 0.f; racc[2] = 0.f; }
    __syncthreads();
    if (lane == 0) {
      atomicAdd(&racc[0], a_loss);
      atomicAdd(&racc[1], a_pos);
      atomicAdd(&racc[2], a_neg);
    }
    __syncthreads();
    if (tid == 0) {
      atomicAdd(&out[0], racc[0]);
      atomicAdd(&out[1], racc[1]);
      atomicAdd(&out[2], racc[2]);
    }
  }
}

extern "C" void kernel_launch(void* const* d_in, const int* in_sizes, int n_in,
                              void* d_out, int out_size, void* d_ws, size_t ws_size,
                              hipStream_t stream) {
  const float* thax_table = (const float*)d_in[0];
  const float* sine_table = (const float*)d_in[1];
  const float* rule_W     = (const float*)d_in[2];
  const float* rule_b     = (const float*)d_in[3];
  const float* eval_w     = (const float*)d_in[4];
  const float* eval_b     = (const float*)d_in[5];
  const float* pos_vals   = (const float*)d_in[6];
  const float* neg_vals   = (const float*)d_in[7];
  const int*   init_thax  = (const int*)d_in[8];
  const int*   init_sine  = (const int*)d_in[9];
  const int*   parents    = (const int*)d_in[10];
  const int*   rules      = (const int*)d_in[11];

  float* out = (float*)d_out;
  char* ws = (char*)d_ws;
  float* sums = (float*)ws;                       // ws+0
  unsigned* bvars = (unsigned*)(ws + 128);        // barrier cnt/gen
  unsigned short* store = (unsigned short*)(ws + ST_OFF);
  int* sorted_idx = (int*)(ws + SI_OFF);
  int* rule_off   = (int*)(ws + RO_OFF);
  unsigned* flags = (unsigned*)(ws + FL_OFF);

  (void)hipMemsetAsync(d_out, 0, 3 * sizeof(float), stream);
  (void)hipMemsetAsync(d_ws, 0, 256, stream);                         // sums+bar
  (void)hipMemsetAsync(ws + FL_OFF, 0, (size_t)LVLS * M * 4, stream); // flags

  void* args[] = {&thax_table, &sine_table, &rule_W, &rule_b, &eval_w, &eval_b,
                  &pos_vals, &neg_vals, &init_thax, &init_sine, &parents,
                  &rules, &store, &sorted_idx, &rule_off, &flags, &sums,
                  &bvars, &out};

  // Prefer 2 blocks per rule (2 blocks/CU) when the cooperative-launch
  // occupancy limit allows it; otherwise fall back to the proven 1-per-rule.
  int occ2 = 0;
  (void)hipOccupancyMaxActiveBlocksPerMultiprocessor(
      &occ2, (const void*)fused_kernel<2>, NTHR, 0);
  if (occ2 >= 2) {
    (void)hipLaunchCooperativeKernel((void*)fused_kernel<2>, dim3(2 * NRULES),
                                     dim3(NTHR), args, 0, stream);
  } else {
    (void)hipLaunchCooperativeKernel((void*)fused_kernel<1>, dim3(NRULES),
                                     dim3(NTHR), args, 0, stream);
  }
}

// Round 6
// 421.900 us; speedup vs baseline: 1.0796x; 1.0796x over previous
//
#include <hip/hip_runtime.h>

#define D      128
#define NINIT  100000
#define LVLS   64
#define M      4096
#define NRULES 256
#define NTOT   (NINIT + LVLS * M)
#define NTHR   512
#define TILE   32

typedef __attribute__((ext_vector_type(8))) short short8;   // 8 bf16 = 4 VGPRs
typedef __attribute__((ext_vector_type(4))) float floatx4;  // MFMA accumulator

// ---------------------------------------------------------------------------
// ws layout (bytes):
//   0      : sums[2] fp32
//   128    : barrier cnt (u32), barrier gen (u32)       (own cacheline)
//   256    : store  bf16 [NTOT][128]          (92,708,864 B)
//   SI_OFF : sorted_idx int [LVLS][M]          (1,048,576 B)
//   RO_OFF : rule_off  int [LVLS][NRULES+1]       (65,792 B)
//   FL_OFF : ready-flags u32 [LVLS*M]          (1,048,576 B)  (memset 0)
// ---------------------------------------------------------------------------
#define ST_OFF 256
#define SI_OFF (ST_OFF + (size_t)NTOT * D * 2)
#define RO_OFF (SI_OFF + (size_t)LVLS * M * 4)
#define FL_OFF (RO_OFF + (size_t)LVLS * (NRULES + 1) * 4)

#define CBAR() asm volatile("" ::: "memory")

__device__ __forceinline__ unsigned short f2bf(float x) {  // RNE fp32->bf16
  unsigned u = __float_as_uint(x);
  u += 0x7fffu + ((u >> 16) & 1u);
  return (unsigned short)(u >> 16);
}

__device__ __forceinline__ float softplusf(float x) {
  return fmaxf(x, 0.f) + log1pf(expf(-fabsf(x)));
}

// --- LLC-coherent (cross-XCD) primitives. SYSTEM-scope relaxed atomics emit
// sc0 sc1 accesses: stores write through to the Infinity Cache (coherence
// point for all 8 XCDs), loads bypass L1/L2 and read it directly.
__device__ __forceinline__ void st_sys(unsigned* p, unsigned v) {
  __hip_atomic_store(p, v, __ATOMIC_RELAXED, __HIP_MEMORY_SCOPE_SYSTEM);
}
__device__ __forceinline__ unsigned ld_sys(const unsigned* p) {
  return __hip_atomic_load(p, __ATOMIC_RELAXED, __HIP_MEMORY_SCOPE_SYSTEM);
}
// Spin with a cap: a protocol bug becomes a wrong answer, not a harness hang.
__device__ __forceinline__ void wait_flag(const unsigned* f) {
  int guard = 1 << 17;
  while (__builtin_expect(ld_sys(f) == 0u, 0) && --guard)
    __builtin_amdgcn_s_sleep(1);
  CBAR();
}

// Heavy grid barrier (release/acquire, flushes+invalidates each XCD's L2).
// Used ONCE, after the init phases: publishes normal-store init data AND
// flushes harness-poison / memset lines, which the flag protocol relies on.
__device__ __forceinline__ void gbar_heavy(unsigned* bcnt, unsigned* bgen) {
  __syncthreads();
  if (threadIdx.x == 0) {
    unsigned g = __hip_atomic_load(bgen, __ATOMIC_RELAXED, __HIP_MEMORY_SCOPE_AGENT);
    unsigned v = __hip_atomic_fetch_add(bcnt, 1u, __ATOMIC_ACQ_REL, __HIP_MEMORY_SCOPE_AGENT);
    if (v == gridDim.x - 1) {
      __hip_atomic_store(bcnt, 0u, __ATOMIC_RELAXED, __HIP_MEMORY_SCOPE_AGENT);
      __hip_atomic_fetch_add(bgen, 1u, __ATOMIC_ACQ_REL, __HIP_MEMORY_SCOPE_AGENT);
    } else {
      while (__hip_atomic_load(bgen, __ATOMIC_RELAXED, __HIP_MEMORY_SCOPE_AGENT) == g)
        __builtin_amdgcn_s_sleep(1);
      __builtin_amdgcn_fence(__ATOMIC_ACQUIRE, "agent");
    }
  }
  __syncthreads();
}

// Light barrier before loss: fence-free (derived rows already at the LLC via
// sc0 stores; consumer caches hold only legally-read clean lines).
__device__ __forceinline__ void gbar_light(unsigned* bcnt, unsigned* bgen) {
  __syncthreads();  // drains vmcnt: this block's stores are out
  if (threadIdx.x == 0) {
    unsigned g = ld_sys(bgen);
    unsigned v = __hip_atomic_fetch_add(bcnt, 1u, __ATOMIC_RELAXED,
                                        __HIP_MEMORY_SCOPE_SYSTEM);
    if (v == gridDim.x - 1) {
      st_sys(bcnt, 0u);
      st_sys(bgen, g + 1u);
    } else {
      int guard = 1 << 22;
      while (ld_sys(bgen) == g && --guard) __builtin_amdgcn_s_sleep(2);
    }
  }
  __syncthreads();
}

// Cursor over rule r's 32-node tiles across all levels (skips empty levels).
__device__ __forceinline__ bool adv_cursor(int r, const int* __restrict__ ro,
                                           int& l, int& t0, int& off, int& cnt) {
  t0 += TILE;
  while (t0 >= cnt) {
    if (++l >= LVLS) return false;
    off = ro[l * (NRULES + 1) + r];
    cnt = ro[l * (NRULES + 1) + r + 1] - off;
    t0 = 0;
  }
  return true;
}

// One cooperative kernel. Block r owns rule r (B-fragments persistent in 32
// VGPRs). 32-node tiles (Poisson(16) counts => ~1 tile per rule-level, no
// straggler serialization). Per tile: rows issued FIRST, then next-tile
// prefetches, then a COUNTED s_waitcnt vmcnt(6) that drains only the row
// stores (vmcnt retires oldest-first) before publishing per-node flags.
__global__ __launch_bounds__(NTHR, 2) void fused_kernel(
    const float* __restrict__ thax_table, const float* __restrict__ sine_table,
    const float* __restrict__ rule_W, const float* __restrict__ rule_b,
    const float* __restrict__ eval_w, const float* __restrict__ eval_b,
    const float* __restrict__ pos, const float* __restrict__ neg,
    const int* __restrict__ init_thax, const int* __restrict__ init_sine,
    const int* __restrict__ parents,  // [LVLS][M][2]
    const int* __restrict__ rules,    // [LVLS][M]
    unsigned short* __restrict__ store, int* __restrict__ sorted_idx,
    int* __restrict__ rule_off, unsigned* __restrict__ flags,
    float* __restrict__ sums, unsigned* __restrict__ bvars,
    float* __restrict__ out) {
  __shared__ unsigned short pe[TILE * 264];  // gather tile: 32 x 256 + pad
  __shared__ unsigned short ot[TILE * 136];  // output tile: 32 x 128 + pad
  __shared__ int s_sid[2][TILE];
  __shared__ int s_cnt[NRULES];
  __shared__ int s_base[NRULES + 1];
  __shared__ float racc[3];

  unsigned* bcnt = bvars;
  unsigned* bgen = bvars + 1;

  const int r = blockIdx.x;
  const int tid = threadIdx.x;
  const int wave = tid >> 6, lane = tid & 63;
  const int col = (wave << 4) + (lane & 15);
  const int node = tid >> 4;   // 0..31: staged node
  const int segq = tid & 15;   // 16B chunk within each parent's 256B row
  const int gid = r * NTHR + tid;
  const int gthreads = NRULES * NTHR;

  // ---- Phase A1: rule-r weight fragments, fp32 global -> bf16 VGPRs (once).
  short8 bf[8];
  {
    const float* Wr = rule_W + (size_t)r * (2 * D * D);
    const int krow_base = (lane >> 4) * 8;
#pragma unroll
    for (int ks = 0; ks < 8; ++ks) {
      union { short8 s; unsigned short us[8]; } c;
#pragma unroll
      for (int j = 0; j < 8; ++j)
        c.us[j] = f2bf(Wr[(size_t)(ks * 32 + krow_base + j) * D + col]);
      bf[ks] = c.s;
    }
  }
  const float bias = rule_b[r * D + col];

  // ---- Phase A2: counting-sort nodes by rule (blocks 0..63, one level each).
  if (r < LVLS) {
    const int l = r;
    const int* rl = rules + (size_t)l * M;
    if (tid < NRULES) s_cnt[tid] = 0;
    __syncthreads();
    for (int m = tid; m < M; m += NTHR) atomicAdd(&s_cnt[rl[m]], 1);
    __syncthreads();
    if (tid == 0) {
      int run = 0;
      for (int q = 0; q < NRULES; ++q) { s_base[q] = run; run += s_cnt[q]; }
      s_base[NRULES] = run;
    }
    __syncthreads();
    if (tid < NRULES) {
      rule_off[(size_t)l * (NRULES + 1) + tid] = s_base[tid];
      s_cnt[tid] = s_base[tid];
    }
    if (tid == 0) rule_off[(size_t)l * (NRULES + 1) + NRULES] = M;
    __syncthreads();
    for (int m = tid; m < M; m += NTHR) {
      int p = atomicAdd(&s_cnt[rl[m]], 1);
      sorted_idx[(size_t)l * M + p] = m;
    }
  }

  // ---- Phase A3: init-node embeddings (all blocks, grid-stride).
  for (int idx = gid; idx < NINIT * 16; idx += gthreads) {
    int nd = idx >> 4, sg = idx & 15;
    const float4* t = (const float4*)(thax_table + (size_t)init_thax[nd] * D) + sg * 2;
    const float4* s = (const float4*)(sine_table + (size_t)init_sine[nd] * D) + sg * 2;
    float4 a0 = t[0], a1 = t[1], b0 = s[0], b1 = s[1];
    float v[8] = {a0.x + b0.x, a0.y + b0.y, a0.z + b0.z, a0.w + b0.w,
                  a1.x + b1.x, a1.y + b1.y, a1.z + b1.z, a1.w + b1.w};
    uint4 pk;
    pk.x = (unsigned)f2bf(v[0]) | ((unsigned)f2bf(v[1]) << 16);
    pk.y = (unsigned)f2bf(v[2]) | ((unsigned)f2bf(v[3]) << 16);
    pk.z = (unsigned)f2bf(v[4]) | ((unsigned)f2bf(v[5]) << 16);
    pk.w = (unsigned)f2bf(v[6]) | ((unsigned)f2bf(v[7]) << 16);
    *(uint4*)(store + (size_t)nd * D + sg * 8) = pk;
  }

  // ---- Phase A4: pos/neg sums.
  {
    float sp = 0.f, sn = 0.f;
    for (int i = gid; i < NTOT; i += gthreads) {
      sp += pos[i];
      sn += neg[i];
    }
    for (int m = 32; m; m >>= 1) {
      sp += __shfl_xor(sp, m, 64);
      sn += __shfl_xor(sn, m, 64);
    }
    if (lane == 0) {
      atomicAdd(&sums[0], sp);
      atomicAdd(&sums[1], sn);
    }
  }

  gbar_heavy(bcnt, bgen);  // publish sort/init/sums; flush poison to LLC

  // ---- Level loop: depth-3 tile pipeline (A=compute, B=rows, C=flags,
  // D=idx), per-node flags, no grid barriers.
  int lL = -1, t0L = 0, offL = 0, cntL = 0;

  bool validA = adv_cursor(r, rule_off, lL, t0L, offL, cntL);
  int lA = lL, t0A = t0L, cntA = cntL;
  int parA0 = 0, parA1 = 0;
  bool lateA0 = false, lateA1 = false;
  uint4 gA0 = {0, 0, 0, 0}, gA1 = {0, 0, 0, 0};
  if (validA) {
    int gj = t0A + node; if (gj > cntA - 1) gj = cntA - 1;
    int sid = sorted_idx[(size_t)lA * M + offL + gj];
    parA0 = parents[((size_t)lA * M + sid) * 2 + 0];
    parA1 = parents[((size_t)lA * M + sid) * 2 + 1];
    if (parA0 >= NINIT) wait_flag(flags + (parA0 - NINIT));
    if (parA1 >= NINIT) wait_flag(flags + (parA1 - NINIT));
    gA0 = *(const uint4*)(store + (size_t)parA0 * D + segq * 8);
    gA1 = *(const uint4*)(store + (size_t)parA1 * D + segq * 8);
    if (segq == 0) s_sid[0][node] = sid;
  }

  bool validB = validA && adv_cursor(r, rule_off, lL, t0L, offL, cntL);
  int lB = lL, t0B = t0L, cntB = cntL;
  int sidB = 0, parB0 = 0, parB1 = 0;
  unsigned fB0 = 1u, fB1 = 1u;
  if (validB) {
    int gj = t0B + node; if (gj > cntB - 1) gj = cntB - 1;
    sidB = sorted_idx[(size_t)lB * M + offL + gj];
    parB0 = parents[((size_t)lB * M + sidB) * 2 + 0];
    parB1 = parents[((size_t)lB * M + sidB) * 2 + 1];
    fB0 = parB0 >= NINIT ? ld_sys(flags + (parB0 - NINIT)) : 1u;
    fB1 = parB1 >= NINIT ? ld_sys(flags + (parB1 - NINIT)) : 1u;
  }

  bool validC = validB && adv_cursor(r, rule_off, lL, t0L, offL, cntL);
  int lC = lL, t0C = t0L, cntC = cntL;
  int sidC = 0, parC0 = 0, parC1 = 0;
  if (validC) {
    int gj = t0C + node; if (gj > cntC - 1) gj = cntC - 1;
    sidC = sorted_idx[(size_t)lC * M + offL + gj];
    parC0 = parents[((size_t)lC * M + sidC) * 2 + 0];
    parC1 = parents[((size_t)lC * M + sidC) * 2 + 1];
  }

  bool validD = validC && adv_cursor(r, rule_off, lL, t0L, offL, cntL);
  int lD = lL, t0D = t0L, offD = offL, cntD = cntL;

  int p = 0;
  while (validA) {
    // (0) late-resolve A (rare). Safe: flags for all our earlier tiles are
    // already published; A's parents are at strictly earlier levels. The
    // parent line was never cached unready (unready lanes gathered a dummy
    // address), so a normal load here cannot hit a stale L2 line.
    if (lateA0) {
      wait_flag(flags + (parA0 - NINIT));
      gA0 = *(const uint4*)(store + (size_t)parA0 * D + segq * 8);
    }
    if (lateA1) {
      wait_flag(flags + (parA1 - NINIT));
      gA1 = *(const uint4*)(store + (size_t)parA1 * D + segq * 8);
    }

    // (1) stage pe (single buffer: previous tile's reads done before the
    // previous ot-sync; these writes come after it).
    *(uint4*)(pe + node * 264 + segq * 8) = gA0;
    *(uint4*)(pe + node * 264 + 128 + segq * 8) = gA1;
    __syncthreads();
    if (validB && segq == 0) s_sid[p ^ 1][node] = sidB;

    // (2) 16 MFMA (two 16-node halves) + ReLU/bias -> transpose tile
    floatx4 acc0 = {0.f, 0.f, 0.f, 0.f}, acc1 = {0.f, 0.f, 0.f, 0.f};
#pragma unroll
    for (int ks = 0; ks < 8; ++ks) {
      short8 a0 = *(const short8*)(pe + (lane & 15) * 264 + ks * 32 + (lane >> 4) * 8);
      short8 a1 = *(const short8*)(pe + (16 + (lane & 15)) * 264 + ks * 32 + (lane >> 4) * 8);
      acc0 = __builtin_amdgcn_mfma_f32_16x16x32_bf16(a0, bf[ks], acc0, 0, 0, 0);
      acc1 = __builtin_amdgcn_mfma_f32_16x16x32_bf16(a1, bf[ks], acc1, 0, 0, 0);
    }
#pragma unroll
    for (int reg = 0; reg < 4; ++reg) {
      int row = (lane >> 4) * 4 + reg;
      float v0 = acc0[reg] + bias;
      float v1 = acc1[reg] + bias;
      ot[row * 136 + col] = f2bf(v0 > 0.f ? v0 : 0.f);
      ot[(16 + row) * 136 + col] = f2bf(v1 > 0.f ? v1 : 0.f);
    }
    __syncthreads();

    // (3) rows(A) FIRST: wave w owns nodes {w, w+8, w+16, w+24}; 4 sc-dword
    // stores per thread. These are the ONLY ops the flag publication must
    // wait on.
    const int n_baseA = NINIT + lA * M;
    int nsid[4]; bool inr[4];
#pragma unroll
    for (int k = 0; k < 4; ++k) {
      int nd = wave + 8 * k;
      nsid[k] = s_sid[p][nd];
      inr[k] = (t0A + nd) < cntA;
      if (inr[k])
        st_sys((unsigned*)(store + (size_t)(n_baseA + nsid[k]) * D) + lane,
               *(const unsigned*)(ot + nd * 136 + lane * 2));
    }
    CBAR();  // keep the prefetches below AFTER the row stores in issue order

    // (4) prefetches for the next tiles (stay in flight across the counted
    // drain). Gathers(B): unconditional instruction; unready lanes read a
    // dummy (init row 0) address so no stale line is ever cached.
    bool lateB0 = validB && parB0 >= NINIT && fB0 == 0u;
    bool lateB1 = validB && parB1 >= NINIT && fB1 == 0u;
    uint4 gB0, gB1;
    {
      const unsigned short* a0 =
          (validB && !lateB0) ? store + (size_t)parB0 * D : store;
      const unsigned short* a1 =
          (validB && !lateB1) ? store + (size_t)parB1 * D : store;
      gB0 = *(const uint4*)(a0 + segq * 8);
      gB1 = *(const uint4*)(a1 + segq * 8);
    }
    unsigned fC0 = 1u, fC1 = 1u;
    if (validC) {
      fC0 = ld_sys(flags + (parC0 >= NINIT ? parC0 - NINIT : 0));
      fC1 = ld_sys(flags + (parC1 >= NINIT ? parC1 - NINIT : 0));
      if (parC0 < NINIT) fC0 = 1u;
      if (parC1 < NINIT) fC1 = 1u;
    }
    int sidD = 0, parD0 = 0, parD1 = 0;
    if (validD) {
      int gj = t0D + node; if (gj > cntD - 1) gj = cntD - 1;
      sidD = sorted_idx[(size_t)lD * M + offD + gj];
      parD0 = parents[((size_t)lD * M + sidD) * 2 + 0];
      parD1 = parents[((size_t)lD * M + sidD) * 2 + 1];
    }
    CBAR();

    // (5) counted drain: with validD, >=6 vmem ops were issued after the 4
    // row stores (2 gathers + 2 flag loads + idx loads); vmcnt(6) therefore
    // retires the rows while the prefetches stay in flight. Tail iterations
    // (validD false) use the full drain.
    if (validD) asm volatile("s_waitcnt vmcnt(6)" ::: "memory");
    else        asm volatile("s_waitcnt vmcnt(0)" ::: "memory");

    // (6) publish flags(A)
    if (lane == 0) {
#pragma unroll
      for (int k = 0; k < 4; ++k)
        if (inr[k]) st_sys(flags + lA * M + nsid[k], 1u);
    }
    CBAR();  // flags issued before any later spin

    // (7) shift pipeline slots
    gA0 = gB0; gA1 = gB1; lateA0 = lateB0; lateA1 = lateB1;
    parA0 = parB0; parA1 = parB1;
    lA = lB; t0A = t0B; cntA = cntB; validA = validB;
    sidB = sidC; parB0 = parC0; parB1 = parC1; fB0 = fC0; fB1 = fC1;
    lB = lC; t0B = t0C; cntB = cntC; validB = validC;
    sidC = sidD; parC0 = parD0; parC1 = parD1;
    lC = lD; t0C = t0D; cntC = cntD; validC = validD;
    validD = validC && adv_cursor(r, rule_off, lL, t0L, offL, cntL);
    lD = lL; t0D = t0L; offD = offL; cntD = cntL;
    p ^= 1;
  }

  gbar_light(bcnt, bgen);  // all rows at LLC; no fences needed

  // ---- Loss phase.
  {
    float a_loss = 0.f, a_pos = 0.f, a_neg = 0.f;
    const float pw = sums[1] / sums[0];
    const float eb = eval_b[0];
    const float4* wv = (const float4*)eval_w;

    for (int nd = gid; nd < NTOT; nd += gthreads) {
      const uint4* v = (const uint4*)(store + (size_t)nd * D);
      float dot = 0.f;
#pragma unroll
      for (int k = 0; k < 16; ++k) {
        uint4 u = v[k];
        float4 w0 = wv[k * 2], w1 = wv[k * 2 + 1];
        dot += __uint_as_float(u.x << 16) * w0.x +
               __uint_as_float(u.x & 0xffff0000u) * w0.y +
               __uint_as_float(u.y << 16) * w0.z +
               __uint_as_float(u.y & 0xffff0000u) * w0.w +
               __uint_as_float(u.z << 16) * w1.x +
               __uint_as_float(u.z & 0xffff0000u) * w1.y +
               __uint_as_float(u.w << 16) * w1.z +
               __uint_as_float(u.w & 0xffff0000u) * w1.w;
      }
      float logit = dot + eb;
      float pp = pos[nd], nn = neg[nd];
      float tot = pp + nn, y = pp / tot;
      a_loss += tot * (pw * y * softplusf(-logit) + (1.f - y) * softplusf(logit));
      if (logit >= 0.f) a_pos += pp; else a_neg += nn;
    }

    for (int m = 32; m; m >>= 1) {
      a_loss += __shfl_xor(a_loss, m, 64);
      a_pos  += __shfl_xor(a_pos,  m, 64);
      a_neg  += __shfl_xor(a_neg,  m, 64);
    }
    if (tid == 0) { racc[0] = 0.f; racc[1] = 0.f; racc[2] = 0.f; }
    __syncthreads();
    if (lane == 0) {
      atomicAdd(&racc[0], a_loss);
      atomicAdd(&racc[1], a_pos);
      atomicAdd(&racc[2], a_neg);
    }
    __syncthreads();
    if (tid == 0) {
      atomicAdd(&out[0], racc[0]);
      atomicAdd(&out[1], racc[1]);
      atomicAdd(&out[2], racc[2]);
    }
  }
}

extern "C" void kernel_launch(void* const* d_in, const int* in_sizes, int n_in,
                              void* d_out, int out_size, void* d_ws, size_t ws_size,
                              hipStream_t stream) {
  const float* thax_table = (const float*)d_in[0];
  const float* sine_table = (const float*)d_in[1];
  const float* rule_W     = (const float*)d_in[2];
  const float* rule_b     = (const float*)d_in[3];
  const float* eval_w     = (const float*)d_in[4];
  const float* eval_b     = (const float*)d_in[5];
  const float* pos_vals   = (const float*)d_in[6];
  const float* neg_vals   = (const float*)d_in[7];
  const int*   init_thax  = (const int*)d_in[8];
  const int*   init_sine  = (const int*)d_in[9];
  const int*   parents    = (const int*)d_in[10];
  const int*   rules      = (const int*)d_in[11];

  float* out = (float*)d_out;
  char* ws = (char*)d_ws;
  float* sums = (float*)ws;                       // ws+0
  unsigned* bvars = (unsigned*)(ws + 128);        // barrier cnt/gen
  unsigned short* store = (unsigned short*)(ws + ST_OFF);
  int* sorted_idx = (int*)(ws + SI_OFF);
  int* rule_off   = (int*)(ws + RO_OFF);
  unsigned* flags = (unsigned*)(ws + FL_OFF);

  (void)hipMemsetAsync(d_out, 0, 3 * sizeof(float), stream);
  (void)hipMemsetAsync(d_ws, 0, 256, stream);                         // sums+bar
  (void)hipMemsetAsync(ws + FL_OFF, 0, (size_t)LVLS * M * 4, stream); // flags

  void* args[] = {&thax_table, &sine_table, &rule_W, &rule_b, &eval_w, &eval_b,
                  &pos_vals, &neg_vals, &init_thax, &init_sine, &parents,
                  &rules, &store, &sorted_idx, &rule_off, &flags, &sums,
                  &bvars, &out};
  (void)hipLaunchCooperativeKernel((void*)fused_kernel, dim3(NRULES),
                                   dim3(NTHR), args, 0, stream);
}